// Round 2
// baseline (216.130 us; speedup 1.0000x reference)
//
#include <hip/hip_runtime.h>

#define N_NODES 50000
#define N_EDGES 600000
#define DIM     128
#define VOCAB   512
#define LN_EPS  1e-5f
#define FIX20   1048576.0f    // 2^20 fixed-point scale for weight sums (26-bit field)
#define WSC     65535.0f      // 16-bit fixed-point scale for edge weights
#define BCAP    64            // fixed CSR bucket capacity (max in-degree << 64)

typedef unsigned int uint;
typedef unsigned long long ull;
typedef unsigned short ushort;
typedef __attribute__((ext_vector_type(8))) short s8v;   // 8 bf16 (4 VGPRs)
typedef __attribute__((ext_vector_type(4))) float f4v;   // 4 fp32 acc
typedef __attribute__((ext_vector_type(4))) int   i4v;
typedef __attribute__((ext_vector_type(4))) float fv4;
typedef __attribute__((ext_vector_type(2))) float f2v;

// round-to-nearest-even fp32 -> bf16 (as uint16 in low bits)
__device__ __forceinline__ uint f2bf(float f) {
    uint u = __float_as_uint(f);
    return (u + 0x7fffu + ((u >> 16) & 1u)) >> 16;
}
__device__ __forceinline__ float bf_lo(uint p) { return __uint_as_float(p << 16); }
__device__ __forceinline__ float bf_hi(uint p) { return __uint_as_float(p & 0xffff0000u); }
// pack word: {count:6 | fixsum:26}, fixsum scaled by 2^20
__device__ __forceinline__ float dis_of(uint pv) {
    return rsqrtf(1.0f + (float)(pv & 0x03ffffffu) * (1.0f / FIX20));
}

// ---------------------------------------------------------------------------
// K1 (fused): blocks [0, nbDeg): per-edge 32-bit atomic {count:6, fixsum:26}
//   -> rank, then DIRECT scatter of a 4-byte record
//   epack[dst*BCAP + rank] = {src:16 | w_fixed16:16}.
//   (nid[src] and dis[src] are both deferred to the agg kernels.)
// blocks [nbDeg, nbDeg+8): layer-1 matmul Hb = emb @ W1 (fp32 -> bf16x2).
// blocks [nbDeg+8, +64): pack W2 into MFMA B-frag order (bf16).
__global__ __launch_bounds__(256) void deg_mm1_kernel(
        const int* __restrict__ ei, const float* __restrict__ ew,
        uint* pack, uint* __restrict__ epack, int E,
        const float* __restrict__ X, const float* __restrict__ W,
        uint* __restrict__ Hb, int M,
        const float* __restrict__ W2, ushort* __restrict__ Wp) {
    __shared__ float Wt[32 * 128];
    __shared__ float Xt[64 * 36];
    int tid = threadIdx.x;
    int nbDeg = (E / 4 + 255) / 256;
    int nmm = (M + 63) / 64;
    if ((int)blockIdx.x < nbDeg) {
        // ---- deg/rank + direct bucket scatter: 4 independent chains ----
        int e0 = (blockIdx.x * 256 + tid) * 4;
        if (e0 >= E) return;
        i4v s4 = __builtin_nontemporal_load((const i4v*)(ei + e0));
        i4v c4 = __builtin_nontemporal_load((const i4v*)(ei + E + e0));
        fv4 w4 = __builtin_nontemporal_load((const fv4*)(ew + e0));
        int   s[4] = {s4.x, s4.y, s4.z, s4.w};
        int   c[4] = {c4.x, c4.y, c4.z, c4.w};
        float w[4] = {w4.x, w4.y, w4.z, w4.w};
        uint r[4];
        #pragma unroll
        for (int k = 0; k < 4; k++) {
            uint a = (1u << 26) | (uint)__float2int_rn(w[k] * FIX20);
            r[k] = atomicAdd(&pack[c[k]], a);
        }
        #pragma unroll
        for (int k = 0; k < 4; k++) {
            uint rk = r[k] >> 26;                        // rank among dst's edges
            uint wq = (uint)__float2int_rn(w[k] * WSC);
            epack[(size_t)c[k] * BCAP + rk] = (uint)s[k] | (wq << 16);
        }
        return;
    }
    if ((int)blockIdx.x >= nbDeg + nmm) {
        // ---- W2 prepack path ----
        int o = (blockIdx.x - nbDeg - nmm) * 256 + tid;    // 0..16383
        int j = o & 7, lane = (o >> 3) & 63, chunk = o >> 9;
        int kc = chunk & 3, nc = chunk >> 2;
        int k = kc * 32 + (lane >> 4) * 8 + j;
        int n = nc * 16 + (lane & 15);
        Wp[o] = (ushort)f2bf(W2[k * 128 + n]);
        return;
    }
    // ---- layer-1 matmul path ----
    int bx = blockIdx.x - nbDeg;
    int tx = tid & 31, ty = tid >> 5;
    int r0 = bx * 64;
    float acc[8][4];
    #pragma unroll
    for (int j = 0; j < 8; j++)
        #pragma unroll
        for (int c = 0; c < 4; c++) acc[j][c] = 0.f;

    for (int kb = 0; kb < 128; kb += 32) {
        __syncthreads();
        #pragma unroll
        for (int q = 0; q < 4; q++) {
            int f = q * 256 + tid;
            ((float4*)Wt)[f] = *(const float4*)(W + kb * 128 + f * 4);
        }
        #pragma unroll
        for (int q = 0; q < 2; q++) {
            int f = q * 256 + tid;
            int row = f >> 3, cs = f & 7;
            int gr = r0 + row;
            float4 xv = make_float4(0.f, 0.f, 0.f, 0.f);
            if (gr < M) xv = *(const float4*)(X + (size_t)gr * 128 + kb + cs * 4);
            *(float4*)(Xt + row * 36 + cs * 4) = xv;
        }
        __syncthreads();
        #pragma unroll
        for (int k = 0; k < 32; k += 4) {
            float wv[4][4];
            #pragma unroll
            for (int kk = 0; kk < 4; kk++) {
                float4 t4 = *(const float4*)(Wt + (k + kk) * 128 + tx * 4);
                wv[kk][0] = t4.x; wv[kk][1] = t4.y; wv[kk][2] = t4.z; wv[kk][3] = t4.w;
            }
            #pragma unroll
            for (int j = 0; j < 8; j++) {
                float4 xv = *(const float4*)(Xt + (ty * 8 + j) * 36 + k);
                float xs[4] = {xv.x, xv.y, xv.z, xv.w};
                #pragma unroll
                for (int kk = 0; kk < 4; kk++)
                    #pragma unroll
                    for (int c = 0; c < 4; c++)
                        acc[j][c] = fmaf(xs[kk], wv[kk][c], acc[j][c]);
            }
        }
    }
    #pragma unroll
    for (int j = 0; j < 8; j++) {
        int gr = r0 + ty * 8 + j;
        if (gr < M) {
            uint p0 = f2bf(acc[j][0]) | (f2bf(acc[j][1]) << 16);
            uint p1 = f2bf(acc[j][2]) | (f2bf(acc[j][3]) << 16);
            ((uint2*)Hb)[(size_t)gr * 32 + tx] = make_uint2(p0, p1);
        }
    }
}

// ---------------------------------------------------------------------------
// K5: MFMA bf16 matmul (layer 2) with per-row int8 quantized output:
// H8[r][c] = round(h2[r][c] * 127/max|row r|).
// rowscale[r] = max|row r|/127 * dis[r]   <- dis FOLDED here so layer-2 agg
// needs only the raw edge weight.
__global__ __launch_bounds__(256) void mm2_mfma(const uint* __restrict__ Xb,
                                                const ushort* __restrict__ Wp,
                                                const uint* __restrict__ pack,
                                                char* __restrict__ H8,
                                                float* __restrict__ rowscale, int M) {
    int wid = (blockIdx.x * 256 + threadIdx.x) >> 6;
    int lane = threadIdx.x & 63;
    int r0 = wid * 16;
    if (r0 >= M) return;                    // M % 16 == 0: no partial tiles
    int quad = lane >> 4, lo = lane & 15;
    const uint* xrow = Xb + (size_t)(r0 + lo) * 64 + quad * 4;
    s8v a[4];
    #pragma unroll
    for (int kc = 0; kc < 4; kc++) a[kc] = *(const s8v*)(xrow + kc * 16);
    f4v acc[8];
    #pragma unroll
    for (int nc = 0; nc < 8; nc++) {
        acc[nc] = (f4v){0.f, 0.f, 0.f, 0.f};
        #pragma unroll
        for (int kc = 0; kc < 4; kc++) {
            s8v b = *(const s8v*)(Wp + (size_t)((nc * 4 + kc) * 64 + lane) * 8);
            acc[nc] = __builtin_amdgcn_mfma_f32_16x16x32_bf16(a[kc], b, acc[nc], 0, 0, 0);
        }
    }
    float m[4];
    #pragma unroll
    for (int r = 0; r < 4; r++) {
        m[r] = 0.f;
        #pragma unroll
        for (int nc = 0; nc < 8; nc++) m[r] = fmaxf(m[r], fabsf(acc[nc][r]));
    }
    #pragma unroll
    for (int o = 1; o <= 8; o <<= 1)
        #pragma unroll
        for (int r = 0; r < 4; r++) m[r] = fmaxf(m[r], __shfl_xor(m[r], o, 64));
    #pragma unroll
    for (int r = 0; r < 4; r++) {
        float inv = (m[r] > 0.f) ? 127.0f / m[r] : 0.f;
        if (lo == 0) {
            int rr = r0 + quad * 4 + r;
            rowscale[rr] = m[r] * (1.0f / 127.0f) * dis_of(pack[rr]);
        }
        char* hp = H8 + (size_t)(r0 + quad * 4 + r) * 128 + lo;
        #pragma unroll
        for (int nc = 0; nc < 8; nc++)
            hp[nc * 16] = (char)__float2int_rn(acc[nc][r] * inv);
    }
}

// ---------------------------------------------------------------------------
// Fused aggregation (fixed-stride buckets) + self-loop + bias + residual + LN.
// One wave per node; lane owns dims {2*lane, 2*lane+1}.
// Records are 4B {src:16 | w_fixed16:16}.
// GI8 (layer 2): rowscale carries dis[src]*scale[src]; row index = src.
// !GI8 (layer 1): row = nid[src] (uniform L2 gather); dis[src] recomputed
//   from pack[src] fixsum (uniform 4B gather + rsqrt).
template<bool RESID_BF, bool OUT_BF, bool GI8>
__global__ __launch_bounds__(256) void agg_ln(const uint* __restrict__ pack,
                                              const uint* __restrict__ epack,
                                              const void* __restrict__ hb,
                                              const float* __restrict__ rowscale,
                                              const int* __restrict__ nid,
                                              const void* __restrict__ resid,
                                              const float* __restrict__ bias,
                                              const float* __restrict__ gamma,
                                              const float* __restrict__ beta,
                                              void* __restrict__ out, int n) {
    int i = (blockIdx.x * 256 + threadIdx.x) >> 6;
    int lane = threadIdx.x & 63;
    if (i >= n) return;
    int iw = __builtin_amdgcn_readfirstlane(i);      // wave-uniform -> s_load
    uint pv = pack[iw];
    int deg = (int)(pv >> 26);
    float dl = dis_of(pv);
    int hri = GI8 ? iw : nid[iw];
    float slo, shi;
    if (GI8) {
        uint ps = ((const ushort*)hb)[(size_t)hri * 64 + lane];
        float sc = rowscale[hri];                    // folded: dl * raw_scale
        slo = sc * (float)(signed char)(ps & 0xffu);
        shi = sc * (float)(signed char)(ps >> 8);
    } else {
        uint ps = ((const uint*)hb)[(size_t)hri * 64 + lane];
        slo = bf_lo(ps); shi = bf_hi(ps);
    }
    // self-loop: final *dl gives dl^2*h (GI8: sc already carries one dl)
    float sx[4] = {GI8 ? slo : dl * slo, 0.f, 0.f, 0.f};
    float sy[4] = {GI8 ? shi : dl * shi, 0.f, 0.f, 0.f};
    const uint* ep = epack + (size_t)iw * BCAP;
    for (int j = 0; j < deg; j += 8) {
        uint er[8];
        #pragma unroll
        for (int k = 0; k < 8; k++) {
            int idx = (j + k < deg) ? j + k : deg - 1;   // clamp to valid record
            er[k] = ep[idx];
        }
        uint qv[8];
        float sc[8];
        #pragma unroll
        for (int k = 0; k < 8; k++) {
            uint src = er[k] & 0xffffu;
            if (GI8) {
                qv[k] = ((const ushort*)hb)[(size_t)src * 64 + lane];
                sc[k] = rowscale[src];               // broadcast (all lanes same)
            } else {
                size_t row = (uint)nid[src];         // uniform gather (L2)
                qv[k] = ((const uint*)hb)[row * 64 + lane];
                sc[k] = (float)(pack[src] & 0x03ffffffu);   // fixsum of src
            }
        }
        #pragma unroll
        for (int k = 0; k < 8; k++) {
            float w = (j + k < deg) ? (float)(er[k] >> 16) * (1.0f / WSC) : 0.f;
            float lo, hi;
            if (GI8) {
                w *= sc[k];                          // raw w * (dis_src*scale_src)
                lo = (float)(signed char)(qv[k] & 0xffu);
                hi = (float)(signed char)(qv[k] >> 8);
            } else {
                w *= rsqrtf(1.0f + sc[k] * (1.0f / FIX20));
                lo = bf_lo(qv[k]); hi = bf_hi(qv[k]);
            }
            sx[k & 3] += w * lo;
            sy[k & 3] += w * hi;
        }
    }
    float acc0 = (sx[0] + sx[1]) + (sx[2] + sx[3]);
    float acc1 = (sy[0] + sy[1]) + (sy[2] + sy[3]);
    float2 xr;
    if (RESID_BF) {
        uint pr = __builtin_nontemporal_load((const uint*)resid + (size_t)hri * 64 + lane);
        xr = make_float2(bf_lo(pr), bf_hi(pr));
    } else {
        xr = ((const float2*)resid)[(size_t)hri * 64 + lane];
    }
    float2 bi = ((const float2*)bias)[lane];
    float v0 = xr.x + dl * acc0 + bi.x;
    float v1 = xr.y + dl * acc1 + bi.y;
    float s1 = v0 + v1, s2 = v0 * v0 + v1 * v1;
    #pragma unroll
    for (int o = 32; o > 0; o >>= 1) {
        s1 += __shfl_xor(s1, o, 64);
        s2 += __shfl_xor(s2, o, 64);
    }
    float mu   = s1 * (1.0f / DIM);
    float var  = s2 * (1.0f / DIM) - mu * mu;
    float rstd = rsqrtf(var + LN_EPS);
    float2 ga = ((const float2*)gamma)[lane];
    float2 be = ((const float2*)beta)[lane];
    float o0 = (v0 - mu) * rstd * ga.x + be.x;
    float o1 = (v1 - mu) * rstd * ga.y + be.y;
    if (OUT_BF) {
        __builtin_nontemporal_store(f2bf(o0) | (f2bf(o1) << 16),
                                    (uint*)out + (size_t)i * 64 + lane);
    } else {
        f2v ov = {o0, o1};
        __builtin_nontemporal_store(ov, (f2v*)((float2*)out + (size_t)i * 64 + lane));
    }
}

// ---------------------------------------------------------------------------
extern "C" void kernel_launch(void* const* d_in, const int* in_sizes, int n_in,
                              void* d_out, int out_size, void* d_ws, size_t ws_size,
                              hipStream_t stream) {
    const int*   node_ids = (const int*)  d_in[0];
    const int*   ei       = (const int*)  d_in[1];   // [2, E]
    const float* ew       = (const float*)d_in[2];
    const float* emb      = (const float*)d_in[3];   // [VOCAB, 128]
    const float* W1       = (const float*)d_in[4];
    const float* b1       = (const float*)d_in[5];
    const float* W2       = (const float*)d_in[6];
    const float* b2       = (const float*)d_in[7];
    const float* g1       = (const float*)d_in[8];
    const float* be1      = (const float*)d_in[9];
    const float* g2       = (const float*)d_in[10];
    const float* be2      = (const float*)d_in[11];
    float* out = (float*)d_out;

    // workspace carve-out (256B aligned)
    char* p = (char*)d_ws;
    auto alloc = [&](size_t bytes) {
        char* r = p;
        p += (bytes + 255) & ~(size_t)255;
        return r;
    };
    char*   h8      = (char*)  alloc((size_t)N_NODES * DIM);       // 6.4 MB int8
    float*  rsc     = (float*) alloc((size_t)N_NODES * 4);         // 200 KB scales
    uint*   x1b     = (uint*)  alloc((size_t)N_NODES * 64 * 4);    // 12.8 MB bf16x2
    uint*   hembB   = (uint*)  alloc((size_t)VOCAB * 64 * 4);      // 128 KB bf16x2
    ushort* Wp      = (ushort*)alloc((size_t)128 * 128 * 2);       // 32 KB B-frags
    uint*   pack    = (uint*)  alloc((size_t)N_NODES * 4);         // 200 KB
    uint*   epack   = (uint*)  alloc((size_t)N_NODES * BCAP * 4);  // 12.8 MB

    int nbDeg = (N_EDGES / 4 + 255) / 256;       // 586
    int nmm = (VOCAB + 63) / 64;                 // 8

    // --- fused: deg atomics + DIRECT 4B-record scatter + layer-1 matmul + W2 prepack ---
    (void)hipMemsetAsync(pack, 0, (size_t)N_NODES * 4, stream);
    deg_mm1_kernel<<<nbDeg + nmm + 64, 256, 0, stream>>>(
        ei, ew, pack, epack, N_EDGES, emb, W1, hembB, VOCAB, W2, Wp);

    // --- Layer 1: bf16 gather table; nid[src] + dis[src] gathered per edge ---
    agg_ln<false, true, false><<<(N_NODES + 3) / 4, 256, 0, stream>>>(
        pack, epack, hembB, nullptr, node_ids, emb, b1, g1, be1, x1b, N_NODES);

    // --- Layer 2: MFMA matmul -> int8 h2 (rowscale folds dis), agg+LN -> out ---
    mm2_mfma<<<(N_NODES / 16 + 3) / 4, 256, 0, stream>>>(x1b, Wp, pack, h8, rsc, N_NODES);
    agg_ln<true, false, true><<<(N_NODES + 3) / 4, 256, 0, stream>>>(
        pack, epack, h8, rsc, nullptr, x1b, b2, g2, be2, out, N_NODES);
}

// Round 3
// 207.228 us; speedup vs baseline: 1.0430x; 1.0430x over previous
//
#include <hip/hip_runtime.h>

#define N_NODES 50000
#define N_EDGES 600000
#define DIM     128
#define VOCAB   512
#define LN_EPS  1e-5f
#define FIX20   1048576.0f    // 2^20 fixed-point scale for weight sums (26-bit field)
#define WSC     65535.0f      // 16-bit fixed-point scale for edge weights
#define BCAP    64            // fixed CSR bucket capacity (max in-degree << 64)

typedef unsigned int uint;
typedef unsigned long long ull;
typedef unsigned short ushort;
typedef __attribute__((ext_vector_type(8))) short s8v;   // 8 bf16 (4 VGPRs)
typedef __attribute__((ext_vector_type(4))) float f4v;   // 4 fp32 acc
typedef __attribute__((ext_vector_type(4))) int   i4v;
typedef __attribute__((ext_vector_type(4))) float fv4;
typedef __attribute__((ext_vector_type(2))) float f2v;

// round-to-nearest-even fp32 -> bf16 (as uint16 in low bits)
__device__ __forceinline__ uint f2bf(float f) {
    uint u = __float_as_uint(f);
    return (u + 0x7fffu + ((u >> 16) & 1u)) >> 16;
}
__device__ __forceinline__ float bf_lo(uint p) { return __uint_as_float(p << 16); }
__device__ __forceinline__ float bf_hi(uint p) { return __uint_as_float(p & 0xffff0000u); }
// pack word: {count:6 | fixsum:26}, fixsum scaled by 2^20
__device__ __forceinline__ float dis_of(uint pv) {
    return rsqrtf(1.0f + (float)(pv & 0x03ffffffu) * (1.0f / FIX20));
}

// ---------------------------------------------------------------------------
// K1 (fused): blocks [0, nbDeg): per-edge 32-bit atomic {count:6, fixsum:26}
//   on pairN[dst].x -> rank, then DIRECT scatter of a 4-byte record
//   epack[dst*BCAP + rank] = {src:16 | w_fixed16:16}.
// blocks [nbDeg, nbDeg+nmm): layer-1 matmul Hb = emb @ W1 (fp32 -> bf16x2).
// remaining blocks: W2 prepack (16384 elems) then pairN[i].y = node_ids[i]
//   (nid words disjoint from the atomic pack words -> no ordering hazard).
__global__ __launch_bounds__(256) void deg_mm1_kernel(
        const int* __restrict__ ei, const float* __restrict__ ew,
        uint2* pairN, const int* __restrict__ nid, uint* __restrict__ epack, int E,
        const float* __restrict__ X, const float* __restrict__ W,
        uint* __restrict__ Hb, int M,
        const float* __restrict__ W2, ushort* __restrict__ Wp) {
    __shared__ float Wt[32 * 128];
    __shared__ float Xt[64 * 36];
    int tid = threadIdx.x;
    int nbDeg = (E / 4 + 255) / 256;
    int nmm = (M + 63) / 64;
    if ((int)blockIdx.x < nbDeg) {
        // ---- deg/rank + direct bucket scatter: 4 independent chains ----
        int e0 = (blockIdx.x * 256 + tid) * 4;
        if (e0 >= E) return;
        i4v s4 = __builtin_nontemporal_load((const i4v*)(ei + e0));
        i4v c4 = __builtin_nontemporal_load((const i4v*)(ei + E + e0));
        fv4 w4 = __builtin_nontemporal_load((const fv4*)(ew + e0));
        int   s[4] = {s4.x, s4.y, s4.z, s4.w};
        int   c[4] = {c4.x, c4.y, c4.z, c4.w};
        float w[4] = {w4.x, w4.y, w4.z, w4.w};
        uint r[4];
        #pragma unroll
        for (int k = 0; k < 4; k++) {
            uint a = (1u << 26) | (uint)__float2int_rn(w[k] * FIX20);
            r[k] = atomicAdd(&((uint*)pairN)[2 * (size_t)c[k]], a);
        }
        #pragma unroll
        for (int k = 0; k < 4; k++) {
            uint rk = r[k] >> 26;                        // rank among dst's edges
            uint wq = (uint)__float2int_rn(w[k] * WSC);
            epack[(size_t)c[k] * BCAP + rk] = (uint)s[k] | (wq << 16);
        }
        return;
    }
    if ((int)blockIdx.x >= nbDeg + nmm) {
        int o = (blockIdx.x - nbDeg - nmm) * 256 + tid;
        if (o < 16384) {
            // ---- W2 prepack path ----
            int j = o & 7, lane = (o >> 3) & 63, chunk = o >> 9;
            int kc = chunk & 3, nc = chunk >> 2;
            int k = kc * 32 + (lane >> 4) * 8 + j;
            int n = nc * 16 + (lane & 15);
            Wp[o] = (ushort)f2bf(W2[k * 128 + n]);
        } else {
            // ---- pairN nid-fill path ----
            int i = o - 16384;
            if (i < N_NODES) ((uint*)pairN)[2 * (size_t)i + 1] = (uint)nid[i];
        }
        return;
    }
    // ---- layer-1 matmul path ----
    int bx = blockIdx.x - nbDeg;
    int tx = tid & 31, ty = tid >> 5;
    int r0 = bx * 64;
    float acc[8][4];
    #pragma unroll
    for (int j = 0; j < 8; j++)
        #pragma unroll
        for (int c = 0; c < 4; c++) acc[j][c] = 0.f;

    for (int kb = 0; kb < 128; kb += 32) {
        __syncthreads();
        #pragma unroll
        for (int q = 0; q < 4; q++) {
            int f = q * 256 + tid;
            ((float4*)Wt)[f] = *(const float4*)(W + kb * 128 + f * 4);
        }
        #pragma unroll
        for (int q = 0; q < 2; q++) {
            int f = q * 256 + tid;
            int row = f >> 3, cs = f & 7;
            int gr = r0 + row;
            float4 xv = make_float4(0.f, 0.f, 0.f, 0.f);
            if (gr < M) xv = *(const float4*)(X + (size_t)gr * 128 + kb + cs * 4);
            *(float4*)(Xt + row * 36 + cs * 4) = xv;
        }
        __syncthreads();
        #pragma unroll
        for (int k = 0; k < 32; k += 4) {
            float wv[4][4];
            #pragma unroll
            for (int kk = 0; kk < 4; kk++) {
                float4 t4 = *(const float4*)(Wt + (k + kk) * 128 + tx * 4);
                wv[kk][0] = t4.x; wv[kk][1] = t4.y; wv[kk][2] = t4.z; wv[kk][3] = t4.w;
            }
            #pragma unroll
            for (int j = 0; j < 8; j++) {
                float4 xv = *(const float4*)(Xt + (ty * 8 + j) * 36 + k);
                float xs[4] = {xv.x, xv.y, xv.z, xv.w};
                #pragma unroll
                for (int kk = 0; kk < 4; kk++)
                    #pragma unroll
                    for (int c = 0; c < 4; c++)
                        acc[j][c] = fmaf(xs[kk], wv[kk][c], acc[j][c]);
            }
        }
    }
    #pragma unroll
    for (int j = 0; j < 8; j++) {
        int gr = r0 + ty * 8 + j;
        if (gr < M) {
            uint p0 = f2bf(acc[j][0]) | (f2bf(acc[j][1]) << 16);
            uint p1 = f2bf(acc[j][2]) | (f2bf(acc[j][3]) << 16);
            ((uint2*)Hb)[(size_t)gr * 32 + tx] = make_uint2(p0, p1);
        }
    }
}

// ---------------------------------------------------------------------------
// K5: MFMA bf16 matmul (layer 2) with per-row int8 quantized output:
// rowscale[r] = max|row r|/127 * dis[r]  (dis folded -> agg2 uses raw w).
__global__ __launch_bounds__(256) void mm2_mfma(const uint* __restrict__ Xb,
                                                const ushort* __restrict__ Wp,
                                                const uint2* __restrict__ pairN,
                                                char* __restrict__ H8,
                                                float* __restrict__ rowscale, int M) {
    int wid = (blockIdx.x * 256 + threadIdx.x) >> 6;
    int lane = threadIdx.x & 63;
    int r0 = wid * 16;
    if (r0 >= M) return;                    // M % 16 == 0: no partial tiles
    int quad = lane >> 4, lo = lane & 15;
    const uint* xrow = Xb + (size_t)(r0 + lo) * 64 + quad * 4;
    s8v a[4];
    #pragma unroll
    for (int kc = 0; kc < 4; kc++) a[kc] = *(const s8v*)(xrow + kc * 16);
    f4v acc[8];
    #pragma unroll
    for (int nc = 0; nc < 8; nc++) {
        acc[nc] = (f4v){0.f, 0.f, 0.f, 0.f};
        #pragma unroll
        for (int kc = 0; kc < 4; kc++) {
            s8v b = *(const s8v*)(Wp + (size_t)((nc * 4 + kc) * 64 + lane) * 8);
            acc[nc] = __builtin_amdgcn_mfma_f32_16x16x32_bf16(a[kc], b, acc[nc], 0, 0, 0);
        }
    }
    float m[4];
    #pragma unroll
    for (int r = 0; r < 4; r++) {
        m[r] = 0.f;
        #pragma unroll
        for (int nc = 0; nc < 8; nc++) m[r] = fmaxf(m[r], fabsf(acc[nc][r]));
    }
    #pragma unroll
    for (int o = 1; o <= 8; o <<= 1)
        #pragma unroll
        for (int r = 0; r < 4; r++) m[r] = fmaxf(m[r], __shfl_xor(m[r], o, 64));
    #pragma unroll
    for (int r = 0; r < 4; r++) {
        float inv = (m[r] > 0.f) ? 127.0f / m[r] : 0.f;
        if (lo == 0) {
            int rr = r0 + quad * 4 + r;
            rowscale[rr] = m[r] * (1.0f / 127.0f) * dis_of(pairN[rr].x);
        }
        char* hp = H8 + (size_t)(r0 + quad * 4 + r) * 128 + lo;
        #pragma unroll
        for (int nc = 0; nc < 8; nc++)
            hp[nc * 16] = (char)__float2int_rn(acc[nc][r] * inv);
    }
}

// ---------------------------------------------------------------------------
// Fused aggregation (fixed-stride buckets) + self-loop + bias + residual + LN.
// One wave per node; lane owns dims {2*lane, 2*lane+1}.
// Latency strategy: batch-load 16 contiguous records up front (4 x uint4
// uniform loads = 1 round trip), then issue ALL 16 level-2 gathers, then ALL
// 16 row gathers -> ~3 serial round trips per wave instead of ~6.
// GI8 (layer 2): rowscale carries dis[src]*scale[src]; row index = src.
// !GI8 (layer 1): pairN[src] = {pack, nid} in ONE gather; dis via rsqrt.
template<bool RESID_BF, bool OUT_BF, bool GI8>
__global__ __launch_bounds__(256) void agg_ln(const uint2* __restrict__ pairN,
                                              const uint* __restrict__ epack,
                                              const void* __restrict__ hb,
                                              const float* __restrict__ rowscale,
                                              const void* __restrict__ resid,
                                              const float* __restrict__ bias,
                                              const float* __restrict__ gamma,
                                              const float* __restrict__ beta,
                                              void* __restrict__ out, int n) {
    int i = (blockIdx.x * 256 + threadIdx.x) >> 6;
    int lane = threadIdx.x & 63;
    if (i >= n) return;
    int iw = __builtin_amdgcn_readfirstlane(i);      // wave-uniform
    uint2 pnw = pairN[iw];
    uint pv = pnw.x;
    int deg = (int)(pv >> 26);
    float dl = dis_of(pv);
    int hri = GI8 ? iw : (int)pnw.y;
    float slo, shi;
    if (GI8) {
        uint ps = ((const ushort*)hb)[(size_t)hri * 64 + lane];
        float sc0 = rowscale[hri];                   // folded: dl * raw_scale
        slo = sc0 * (float)(signed char)(ps & 0xffu);
        shi = sc0 * (float)(signed char)(ps >> 8);
    } else {
        uint ps = ((const uint*)hb)[(size_t)hri * 64 + lane];
        slo = bf_lo(ps); shi = bf_hi(ps);
    }
    // self-loop: final *dl gives dl^2*h (GI8: sc already carries one dl)
    float sx[4] = {GI8 ? slo : dl * slo, 0.f, 0.f, 0.f};
    float sy[4] = {GI8 ? shi : dl * shi, 0.f, 0.f, 0.f};
    const uint* ep = epack + (size_t)iw * BCAP;

    for (int j0 = 0; j0 < deg; j0 += 16) {
        // --- 16 records in one shot (bucket always has 64 allocated slots) ---
        uint4 rv0 = ((const uint4*)(ep + j0))[0];
        uint4 rv1 = ((const uint4*)(ep + j0))[1];
        uint4 rv2 = ((const uint4*)(ep + j0))[2];
        uint4 rv3 = ((const uint4*)(ep + j0))[3];
        uint rec[16] = {rv0.x, rv0.y, rv0.z, rv0.w,
                        rv1.x, rv1.y, rv1.z, rv1.w,
                        rv2.x, rv2.y, rv2.z, rv2.w,
                        rv3.x, rv3.y, rv3.z, rv3.w};
        uint src[16];
        #pragma unroll
        for (int k = 0; k < 16; k++)
            src[k] = (j0 + k < deg) ? (rec[k] & 0xffffu) : 0u;   // clamp -> safe row
        uint qv[16];
        float scv[16];
        if (GI8) {
            #pragma unroll
            for (int k = 0; k < 16; k++)
                qv[k] = ((const ushort*)hb)[(size_t)src[k] * 64 + lane];
            #pragma unroll
            for (int k = 0; k < 16; k++)
                scv[k] = rowscale[src[k]];
        } else {
            uint2 pnk[16];
            #pragma unroll
            for (int k = 0; k < 16; k++)
                pnk[k] = pairN[src[k]];              // {pack, nid} one gather
            #pragma unroll
            for (int k = 0; k < 16; k++)
                qv[k] = ((const uint*)hb)[(size_t)pnk[k].y * 64 + lane];
            #pragma unroll
            for (int k = 0; k < 16; k++)
                scv[k] = (float)(pnk[k].x & 0x03ffffffu);
        }
        #pragma unroll
        for (int k = 0; k < 16; k++) {
            float w = (j0 + k < deg) ? (float)(rec[k] >> 16) * (1.0f / WSC) : 0.f;
            float lo, hi;
            if (GI8) {
                w *= scv[k];                         // raw w * (dis_src*scale_src)
                lo = (float)(signed char)(qv[k] & 0xffu);
                hi = (float)(signed char)(qv[k] >> 8);
            } else {
                w *= rsqrtf(1.0f + scv[k] * (1.0f / FIX20));
                lo = bf_lo(qv[k]); hi = bf_hi(qv[k]);
            }
            sx[k & 3] += w * lo;
            sy[k & 3] += w * hi;
        }
    }
    float acc0 = (sx[0] + sx[1]) + (sx[2] + sx[3]);
    float acc1 = (sy[0] + sy[1]) + (sy[2] + sy[3]);
    float2 xr;
    if (RESID_BF) {
        uint pr = __builtin_nontemporal_load((const uint*)resid + (size_t)hri * 64 + lane);
        xr = make_float2(bf_lo(pr), bf_hi(pr));
    } else {
        xr = ((const float2*)resid)[(size_t)hri * 64 + lane];
    }
    float2 bi = ((const float2*)bias)[lane];
    float v0 = xr.x + dl * acc0 + bi.x;
    float v1 = xr.y + dl * acc1 + bi.y;
    float s1 = v0 + v1, s2 = v0 * v0 + v1 * v1;
    #pragma unroll
    for (int o = 32; o > 0; o >>= 1) {
        s1 += __shfl_xor(s1, o, 64);
        s2 += __shfl_xor(s2, o, 64);
    }
    float mu   = s1 * (1.0f / DIM);
    float var  = s2 * (1.0f / DIM) - mu * mu;
    float rstd = rsqrtf(var + LN_EPS);
    float2 ga = ((const float2*)gamma)[lane];
    float2 be = ((const float2*)beta)[lane];
    float o0 = (v0 - mu) * rstd * ga.x + be.x;
    float o1 = (v1 - mu) * rstd * ga.y + be.y;
    if (OUT_BF) {
        __builtin_nontemporal_store(f2bf(o0) | (f2bf(o1) << 16),
                                    (uint*)out + (size_t)i * 64 + lane);
    } else {
        f2v ov = {o0, o1};
        __builtin_nontemporal_store(ov, (f2v*)((float2*)out + (size_t)i * 64 + lane));
    }
}

// ---------------------------------------------------------------------------
extern "C" void kernel_launch(void* const* d_in, const int* in_sizes, int n_in,
                              void* d_out, int out_size, void* d_ws, size_t ws_size,
                              hipStream_t stream) {
    const int*   node_ids = (const int*)  d_in[0];
    const int*   ei       = (const int*)  d_in[1];   // [2, E]
    const float* ew       = (const float*)d_in[2];
    const float* emb      = (const float*)d_in[3];   // [VOCAB, 128]
    const float* W1       = (const float*)d_in[4];
    const float* b1       = (const float*)d_in[5];
    const float* W2       = (const float*)d_in[6];
    const float* b2       = (const float*)d_in[7];
    const float* g1       = (const float*)d_in[8];
    const float* be1      = (const float*)d_in[9];
    const float* g2       = (const float*)d_in[10];
    const float* be2      = (const float*)d_in[11];
    float* out = (float*)d_out;

    // workspace carve-out (256B aligned)
    char* p = (char*)d_ws;
    auto alloc = [&](size_t bytes) {
        char* r = p;
        p += (bytes + 255) & ~(size_t)255;
        return r;
    };
    char*   h8      = (char*)  alloc((size_t)N_NODES * DIM);       // 6.4 MB int8
    float*  rsc     = (float*) alloc((size_t)N_NODES * 4);         // 200 KB scales
    uint*   x1b     = (uint*)  alloc((size_t)N_NODES * 64 * 4);    // 12.8 MB bf16x2
    uint*   hembB   = (uint*)  alloc((size_t)VOCAB * 64 * 4);      // 128 KB bf16x2
    ushort* Wp      = (ushort*)alloc((size_t)128 * 128 * 2);       // 32 KB B-frags
    uint2*  pairN   = (uint2*) alloc((size_t)N_NODES * 8);         // 400 KB {pack,nid}
    uint*   epack   = (uint*)  alloc((size_t)N_NODES * BCAP * 4);  // 12.8 MB

    int nbDeg = (N_EDGES / 4 + 255) / 256;       // 586
    int nmm = (VOCAB + 63) / 64;                 // 8
    int nTail = 64 + (N_NODES + 255) / 256;      // W2 prepack + nid fill = 260

    // --- fused: deg atomics + 4B-record scatter + layer-1 matmul + W2/nid prep ---
    (void)hipMemsetAsync(pairN, 0, (size_t)N_NODES * 8, stream);
    deg_mm1_kernel<<<nbDeg + nmm + nTail, 256, 0, stream>>>(
        ei, ew, pairN, node_ids, epack, N_EDGES, emb, W1, hembB, VOCAB, W2, Wp);

    // --- Layer 1: bf16 gather table; {dis,nid}[src] in one pairN gather ---
    agg_ln<false, true, false><<<(N_NODES + 3) / 4, 256, 0, stream>>>(
        pairN, epack, hembB, nullptr, emb, b1, g1, be1, x1b, N_NODES);

    // --- Layer 2: MFMA matmul -> int8 h2 (rowscale folds dis), agg+LN -> out ---
    mm2_mfma<<<(N_NODES / 16 + 3) / 4, 256, 0, stream>>>(x1b, Wp, pairN, h8, rsc, N_NODES);
    agg_ln<true, false, true><<<(N_NODES + 3) / 4, 256, 0, stream>>>(
        pairN, epack, h8, rsc, x1b, b2, g2, be2, out, N_NODES);
}